// Round 5
// baseline (319.731 us; speedup 1.0000x reference)
//
#include <hip/hip_runtime.h>
#include <math.h>

#define L_   4096
#define DM_  512
#define B_   4
#define H_   8
#define DK_  64
#define MTOT (B_*L_)      // 16384
#define TOPK 16

typedef __bf16 bf16x8 __attribute__((ext_vector_type(8)));
typedef float  f32x4  __attribute__((ext_vector_type(4)));

// ---------------------------------------------------------------- helpers ---
__device__ __forceinline__ void splitf(float x, unsigned short& h, unsigned short& l) {
  unsigned int u = __float_as_uint(x);
  h = (unsigned short)(u >> 16);                       // truncated hi
  float hf = __uint_as_float(u & 0xFFFF0000u);
  l = (unsigned short)(__float_as_uint(x - hf) >> 16); // truncated lo
}
__device__ __forceinline__ unsigned short f2bf_rne(float f) {
  unsigned int u = __float_as_uint(f);
  return (unsigned short)((u + 0x7FFFu + ((u >> 16) & 1u)) >> 16);
}
__device__ __forceinline__ float bf2f(unsigned short u) {
  return __uint_as_float(((unsigned int)u) << 16);
}

// async 16B/lane global->LDS stage of a 128x32 bf16 tile from a row-major
// source with row stride 512 elements. LDS layout: [128][32] contiguous.
__device__ __forceinline__ void stage_tile_async(const unsigned short* __restrict__ g,
                                                 int row0, int k0,
                                                 unsigned short* lds, int tid) {
  const int wave = tid >> 6;
#pragma unroll
  for (int it = 0; it < 2; ++it) {
    int slot = it * 256 + tid;          // 0..511
    int row  = slot >> 2;               // 0..127
    int ch   = slot & 3;                // 16B chunk within 64B row
    const unsigned short* gp = g + (size_t)(row0 + row) * 512 + k0 + ch * 8;
    unsigned short* lp = lds + (size_t)(it * 256 + wave * 64) * 8;  // wave-uniform base
    __builtin_amdgcn_global_load_lds(
        (const __attribute__((address_space(1))) unsigned int*)gp,
        (__attribute__((address_space(3))) unsigned int*)lp, 16, 0, 0);
  }
}

// =============== fused QKV GEMM: [Q|K|V] = x @ [Wq|Wk|Wv]^T + b =============
// M=16384, N=1536 (3 segs of 512), K=512. 128x128 tile, BK=32, 4 waves.
// 2-pass: Ah*(Bh) + Ah*(Bl); A = x in bf16 (RNE), B split exactly.
// seg 0 -> Qb bf16 [b][h][d][t]; seg 1 -> Kb bf16 [b][h][d][t];
// seg 2 -> Vv bf16 [b][h][t][d].
__global__ __launch_bounds__(256)
void qkv_gemm(const unsigned short* __restrict__ xh,
              const unsigned short* __restrict__ Wh, const unsigned short* __restrict__ Wl,
              const float* __restrict__ bq, const float* __restrict__ bk,
              const float* __restrict__ bv,
              unsigned short* __restrict__ Qb, unsigned short* __restrict__ Kb,
              unsigned short* __restrict__ Vv)
{
  __shared__ __attribute__((aligned(16))) unsigned short AhS[128 * 32];
  __shared__ __attribute__((aligned(16))) unsigned short BhS[128 * 32];
  __shared__ __attribute__((aligned(16))) unsigned short BlS[128 * 32];

  const int tid  = threadIdx.x;
  const int lane = tid & 63, wave = tid >> 6;
  const int m0 = blockIdx.x * 128, n0 = blockIdx.y * 128;
  const int wm = (wave >> 1) * 64, wn = (wave & 1) * 64;
  const int fr = lane & 15, fq = lane >> 4;

  f32x4 acc[4][4];
#pragma unroll
  for (int i = 0; i < 4; i++)
#pragma unroll
    for (int j = 0; j < 4; j++) acc[i][j] = (f32x4){0.f, 0.f, 0.f, 0.f};

  for (int k0 = 0; k0 < 512; k0 += 32) {
    stage_tile_async(xh, m0, k0, AhS, tid);
    stage_tile_async(Wh, n0, k0, BhS, tid);
    stage_tile_async(Wl, n0, k0, BlS, tid);
    __syncthreads();

    bf16x8 ah[4], bh[4], bl[4];
#pragma unroll
    for (int t = 0; t < 4; ++t) {
      ah[t] = *(const bf16x8*)&AhS[(wm + t * 16 + fr) * 32 + fq * 8];
      bh[t] = *(const bf16x8*)&BhS[(wn + t * 16 + fr) * 32 + fq * 8];
      bl[t] = *(const bf16x8*)&BlS[(wn + t * 16 + fr) * 32 + fq * 8];
    }
#pragma unroll
    for (int mt = 0; mt < 4; ++mt)
#pragma unroll
      for (int nt = 0; nt < 4; ++nt) {
        acc[mt][nt] = __builtin_amdgcn_mfma_f32_16x16x32_bf16(ah[mt], bh[nt], acc[mt][nt], 0, 0, 0);
        acc[mt][nt] = __builtin_amdgcn_mfma_f32_16x16x32_bf16(ah[mt], bl[nt], acc[mt][nt], 0, 0, 0);
      }
    __syncthreads();
  }

  const int seg = (int)(blockIdx.y >> 2);   // 0:Q 1:K 2:V (block-uniform)
  const float* bias = (seg == 0) ? bq : (seg == 1) ? bk : bv;
  const int nseg0 = seg * 512;
  unsigned short* QKdst = (seg == 0) ? Qb : Kb;

#pragma unroll
  for (int nt = 0; nt < 4; ++nt) {
    const int n  = n0 + wn + nt * 16 + fr;
    const int nl = n - nseg0;
    const float bb = bias[nl];
    const int h = nl >> 6, d = nl & 63;
#pragma unroll
    for (int mt = 0; mt < 4; ++mt) {
      const int mb = m0 + wm + mt * 16 + fq * 4;
      f32x4 a = acc[mt][nt];
      if (seg < 2) {
        const int b = mb >> 12, l0 = mb & (L_ - 1);
        ushort4 st;
        st.x = f2bf_rne(a[0] + bb); st.y = f2bf_rne(a[1] + bb);
        st.z = f2bf_rne(a[2] + bb); st.w = f2bf_rne(a[3] + bb);
        *(ushort4*)(QKdst + ((size_t)(b * H_ + h) * DK_ + d) * L_ + l0) = st;
      } else {
#pragma unroll
        for (int r = 0; r < 4; ++r) {
          int m = mb + r;
          int b = m >> 12, l = m & (L_ - 1);
          Vv[((size_t)(b * H_ + h) * L_ + l) * DK_ + d] = f2bf_rne(a[r] + bb);
        }
      }
    }
  }
}

// ====================== O GEMM: out = ctx @ Wo^T + bias =====================
__global__ __launch_bounds__(256)
void o_gemm(const unsigned short* __restrict__ Ah,
            const unsigned short* __restrict__ Bh, const unsigned short* __restrict__ Bl,
            const float* __restrict__ bias, float* __restrict__ Cout)
{
  __shared__ __attribute__((aligned(16))) unsigned short AhS[128 * 32];
  __shared__ __attribute__((aligned(16))) unsigned short BhS[128 * 32];
  __shared__ __attribute__((aligned(16))) unsigned short BlS[128 * 32];

  const int tid  = threadIdx.x;
  const int lane = tid & 63, wave = tid >> 6;
  const int m0 = blockIdx.x * 128, n0 = blockIdx.y * 128;
  const int wm = (wave >> 1) * 64, wn = (wave & 1) * 64;
  const int fr = lane & 15, fq = lane >> 4;

  f32x4 acc[4][4];
#pragma unroll
  for (int i = 0; i < 4; i++)
#pragma unroll
    for (int j = 0; j < 4; j++) acc[i][j] = (f32x4){0.f, 0.f, 0.f, 0.f};

  for (int k0 = 0; k0 < 512; k0 += 32) {
    stage_tile_async(Ah, m0, k0, AhS, tid);
    stage_tile_async(Bh, n0, k0, BhS, tid);
    stage_tile_async(Bl, n0, k0, BlS, tid);
    __syncthreads();

    bf16x8 ah[4], bh[4], bl[4];
#pragma unroll
    for (int t = 0; t < 4; ++t) {
      ah[t] = *(const bf16x8*)&AhS[(wm + t * 16 + fr) * 32 + fq * 8];
      bh[t] = *(const bf16x8*)&BhS[(wn + t * 16 + fr) * 32 + fq * 8];
      bl[t] = *(const bf16x8*)&BlS[(wn + t * 16 + fr) * 32 + fq * 8];
    }
#pragma unroll
    for (int mt = 0; mt < 4; ++mt)
#pragma unroll
      for (int nt = 0; nt < 4; ++nt) {
        acc[mt][nt] = __builtin_amdgcn_mfma_f32_16x16x32_bf16(ah[mt], bh[nt], acc[mt][nt], 0, 0, 0);
        acc[mt][nt] = __builtin_amdgcn_mfma_f32_16x16x32_bf16(ah[mt], bl[nt], acc[mt][nt], 0, 0, 0);
      }
    __syncthreads();
  }

#pragma unroll
  for (int nt = 0; nt < 4; ++nt) {
    const int n = n0 + wn + nt * 16 + fr;
    const float bb = bias[n];
#pragma unroll
    for (int mt = 0; mt < 4; ++mt) {
      const int mb = m0 + wm + mt * 16 + fq * 4;
      f32x4 a = acc[mt][nt];
#pragma unroll
      for (int r = 0; r < 4; ++r) {
        int m = mb + r;
        Cout[(size_t)m * DM_ + n] = a[r] + bb;
      }
    }
  }
}

// ============== one-shot: x -> bf16 (RNE); 4 weights -> hi/lo split =========
// chunks: x = 2,097,152 float4; each W = 65,536 float4. total 2,359,296.
__global__ __launch_bounds__(256)
void split_all(const float* __restrict__ x,  const float* __restrict__ Wq,
               const float* __restrict__ Wk, const float* __restrict__ Wv,
               const float* __restrict__ Wo,
               unsigned short* __restrict__ xh,
               unsigned short* __restrict__ Wqkvh, unsigned short* __restrict__ Wqkvl,
               unsigned short* __restrict__ Woh,   unsigned short* __restrict__ Wol)
{
  int i = blockIdx.x * 256 + threadIdx.x;
  if (i < 2097152) {
    float4 v = ((const float4*)x)[i];
    ushort4 h;
    h.x = f2bf_rne(v.x); h.y = f2bf_rne(v.y);
    h.z = f2bf_rne(v.z); h.w = f2bf_rne(v.w);
    ((ushort4*)xh)[i] = h;
    return;
  }
  int j = i - 2097152; int seg = j >> 16; int off = j & 65535;
  const float* src; unsigned short* dh; unsigned short* dl;
  if (seg == 0)      { src = Wq; dh = Wqkvh;          dl = Wqkvl; }
  else if (seg == 1) { src = Wk; dh = Wqkvh + 262144; dl = Wqkvl + 262144; }
  else if (seg == 2) { src = Wv; dh = Wqkvh + 524288; dl = Wqkvl + 524288; }
  else               { src = Wo; dh = Woh;            dl = Wol; }
  float4 v = ((const float4*)src)[off];
  ushort4 h, l;
  splitf(v.x, h.x, l.x); splitf(v.y, h.y, l.y);
  splitf(v.z, h.z, l.z); splitf(v.w, h.w, l.w);
  ((ushort4*)dh)[off] = h;
  ((ushort4*)dl)[off] = l;
}

// ==================== FFT: radix-16 Stockham, N=4096, 3 stages ==============
// Stage 1 is computed from registers (inputs loaded directly), stages 16/256
// go through LDS with pad-swizzle addr' = a + (a>>4).
#define FPAD(a) ((a) + ((a) >> 4))
#define LDSN 4352

__device__ __forceinline__ float2 cmul(float2 a, float2 b) {
  return make_float2(a.x * b.x - a.y * b.y, a.x * b.y + a.y * b.x);
}

__device__ __forceinline__ void dft16(float2* x)
{
  const float C1 = 0.9238795325112867f, S1 = 0.3826834323650898f;
  const float C2 = 0.7071067811865476f;
  const float2 w16[16] = {
    { 1.f, 0.f}, { C1,-S1}, { C2,-C2}, { S1,-C1},
    { 0.f,-1.f}, {-S1,-C1}, {-C2,-C2}, {-C1,-S1},
    {-1.f, 0.f}, {-C1, S1}, {-C2, C2}, {-S1, C1},
    { 0.f, 1.f}, { S1, C1}, { C2, C2}, { C1, S1}};
  float2 y[16];
#pragma unroll
  for (int jj = 0; jj < 4; jj++) {
    float2 a = x[jj], b = x[jj + 4], c = x[jj + 8], d = x[jj + 12];
    float2 t0 = make_float2(a.x + c.x, a.y + c.y);
    float2 t1 = make_float2(a.x - c.x, a.y - c.y);
    float2 t2 = make_float2(b.x + d.x, b.y + d.y);
    float2 t3 = make_float2(b.x - d.x, b.y - d.y);
    float2 u0 = make_float2(t0.x + t2.x, t0.y + t2.y);
    float2 u2 = make_float2(t0.x - t2.x, t0.y - t2.y);
    float2 u1 = make_float2(t1.x + t3.y, t1.y - t3.x);
    float2 u3 = make_float2(t1.x - t3.y, t1.y + t3.x);
    y[4 * jj + 0] = u0;
    y[4 * jj + 1] = cmul(u1, w16[(jj * 1) & 15]);
    y[4 * jj + 2] = cmul(u2, w16[(jj * 2) & 15]);
    y[4 * jj + 3] = cmul(u3, w16[(jj * 3) & 15]);
  }
#pragma unroll
  for (int jj = 0; jj < 4; jj++) {
    float2 a = y[jj], b = y[jj + 4], c = y[jj + 8], d = y[jj + 12];
    float2 t0 = make_float2(a.x + c.x, a.y + c.y);
    float2 t1 = make_float2(a.x - c.x, a.y - c.y);
    float2 t2 = make_float2(b.x + d.x, b.y + d.y);
    float2 t3 = make_float2(b.x - d.x, b.y - d.y);
    x[jj + 0]  = make_float2(t0.x + t2.x, t0.y + t2.y);
    x[jj + 8]  = make_float2(t0.x - t2.x, t0.y - t2.y);
    x[jj + 4]  = make_float2(t1.x + t3.y, t1.y - t3.x);
    x[jj + 12] = make_float2(t1.x - t3.y, t1.y + t3.x);
  }
}

// stage 1 from registers: x[r] = z[j + 256r]; writes padded stage-1 output.
__device__ __forceinline__ void fft_stage1_reg(float2* x, float2* __restrict__ Ys, int j)
{
  dft16(x);
  float ang = -1.5339807878856412e-3f * (float)j;   // -2*pi/4096 * j
  float2 w; __sincosf(ang, &w.y, &w.x);
  float2 t = w;
#pragma unroll
  for (int k = 1; k < 16; k++) { x[k] = cmul(x[k], t); t = cmul(t, w); }
  // out index 16j+k -> FPAD = 17j+k (contiguous per thread)
  float2* yp = Ys + 17 * j;
#pragma unroll
  for (int k = 0; k < 16; k++) yp[k] = x[k];
}

template<int S, bool PADOUT>
__device__ __forceinline__ void fft_stage(const float2* __restrict__ Xs,
                                          float2* __restrict__ Ys, int j)
{
  float2 x[16];
#pragma unroll
  for (int r = 0; r < 16; r++) { int a = j + 256 * r; x[r] = Xs[FPAD(a)]; }
  dft16(x);
  if (S < 256) {
    int p = (S == 1) ? j : (j >> 4);
    float ang = -1.5339807878856412e-3f * (float)(p * S);
    float2 w; __sincosf(ang, &w.y, &w.x);
    float2 t = w;
#pragma unroll
    for (int k = 1; k < 16; k++) { x[k] = cmul(x[k], t); t = cmul(t, w); }
  }
  const int q = j & (S - 1);
  const int base = q + ((j - q) << 4);   // q + 16*p*S
#pragma unroll
  for (int k = 0; k < 16; k++) {
    int a = base + k * S;
    Ys[PADOUT ? FPAD(a) : a] = x[k];
  }
}

// One workgroup per (b*H+h, d-group of 2). grid (32, 32). Q,K in bf16.
__global__ __launch_bounds__(256)
void fft_fwd_kernel(const unsigned short* __restrict__ Qb,
                    const unsigned short* __restrict__ Kb,
                    float* __restrict__ P)
{
  __shared__ __attribute__((aligned(16))) float2 Abuf[LDSN];
  __shared__ __attribute__((aligned(16))) float2 Bbuf[LDSN];
  const int tid = threadIdx.x;
  const int bh = blockIdx.x;      // 0..31
  const int g  = blockIdx.y;      // 0..31
  float2 accv[16];
#pragma unroll
  for (int r = 0; r < 16; r++) accv[r] = make_float2(0.f, 0.f);

  for (int dd = 0; dd < 2; dd++) {
    int d = g * 2 + dd;
    const unsigned short* q = Qb + ((size_t)bh * DK_ + d) * L_;
    const unsigned short* k = Kb + ((size_t)bh * DK_ + d) * L_;
    float2 x[16];
#pragma unroll
    for (int r = 0; r < 16; r++) {
      int t = tid + 256 * r;
      x[r] = make_float2(bf2f(q[t]), bf2f(k[t]));   // z = q + i*k
    }
    __syncthreads();               // prev channel's unpack reads of Abuf done
    fft_stage1_reg(x, Abuf, tid);
    __syncthreads();
    fft_stage<16, true>(Abuf, Bbuf, tid);
    __syncthreads();
    fft_stage<256, false>(Bbuf, Abuf, tid);   // result in Abuf, unpadded
    __syncthreads();
#pragma unroll
    for (int r = 0; r < 16; r++) {
      int f = tid + 256 * r;
      float2 zf = Abuf[f];
      float2 zc = Abuf[(L_ - f) & (L_ - 1)];
      float qr = 0.5f * (zf.x + zc.x);       // Qf = (Z[f]+conj(Z[N-f]))/2
      float qi = 0.5f * (zf.y - zc.y);
      float kr = 0.5f * (zf.y + zc.y);       // Kf = (Z[f]-conj(Z[N-f]))/(2i)
      float ki = 0.5f * (zc.x - zf.x);
      accv[r].x += qr * kr + qi * ki;        // G = Qf * conj(Kf)
      accv[r].y += qi * kr - qr * ki;
    }
  }
  float2* Pp = (float2*)P + ((size_t)bh * 32 + g) * L_;
#pragma unroll
  for (int r = 0; r < 16; r++) Pp[tid + 256 * r] = accv[r];
}

// ================= fused: sum partials + inverse FFT + top-16 + softmax =====
__global__ __launch_bounds__(256)
void fft_inv_topk_kernel(const float* __restrict__ P, float* __restrict__ w,
                         int* __restrict__ delays)
{
  __shared__ __attribute__((aligned(16))) float2 Abuf[LDSN];
  __shared__ __attribute__((aligned(16))) float2 Bbuf[LDSN];
  __shared__ float swv[4];
  __shared__ int   swi[4];
  __shared__ float topv[TOPK];
  __shared__ int   topi[TOPK];
  __shared__ int   winner;
  const int tid = threadIdx.x;
  const int bh = blockIdx.x;
  const float2* Pp = (const float2*)P + (size_t)bh * 32 * L_;

  float2 x[16];
#pragma unroll
  for (int r = 0; r < 16; r++) {
    int f = tid + 256 * r;
    float sr = 0.f, si = 0.f;
#pragma unroll
    for (int g = 0; g < 32; g++) {
      float2 v = Pp[(size_t)g * L_ + f];
      sr += v.x; si += v.y;
    }
    x[r] = make_float2(sr, -si);       // conj
  }
  fft_stage1_reg(x, Abuf, tid);
  __syncthreads();
  fft_stage<16, true>(Abuf, Bbuf, tid);
  __syncthreads();
  fft_stage<256, false>(Bbuf, Abuf, tid);   // result in Abuf, unpadded
  __syncthreads();

  const float scale = 1.0f / ((float)L_ * (float)DK_);
  float v[16];
#pragma unroll
  for (int r = 0; r < 16; r++) v[r] = Abuf[tid + 256 * r].x * scale;

  for (int it = 0; it < TOPK; it++) {
    float bv = -INFINITY; int bi = 0;
#pragma unroll
    for (int r = 0; r < 16; r++) {
      if (v[r] > bv) { bv = v[r]; bi = tid + 256 * r; }
    }
#pragma unroll
    for (int off = 32; off > 0; off >>= 1) {
      float ov = __shfl_down(bv, off, 64);
      int   oi = __shfl_down(bi, off, 64);
      if (ov > bv || (ov == bv && oi < bi)) { bv = ov; bi = oi; }
    }
    if ((tid & 63) == 0) { swv[tid >> 6] = bv; swi[tid >> 6] = bi; }
    __syncthreads();
    if (tid == 0) {
      float mv = swv[0]; int mi = swi[0];
#pragma unroll
      for (int q = 1; q < 4; q++)
        if (swv[q] > mv || (swv[q] == mv && swi[q] < mi)) { mv = swv[q]; mi = swi[q]; }
      topv[it] = mv; topi[it] = mi; winner = mi;
    }
    __syncthreads();
    int win = winner;
    if ((win & 255) == tid) v[win >> 8] = -INFINITY;
  }
  if (tid == 0) {
    float mx = topv[0];
    for (int j = 1; j < TOPK; j++) mx = fmaxf(mx, topv[j]);
    float e[TOPK]; float se = 0.f;
    for (int j = 0; j < TOPK; j++) { e[j] = expf(topv[j] - mx); se += e[j]; }
    float inv = 1.0f / se;
    for (int j = 0; j < TOPK; j++) {
      w[bh * TOPK + j] = e[j] * inv;
      delays[bh * TOPK + j] = topi[j];
    }
  }
}

// ============================ delay gather ==================================
// V bf16 [b][h][t][d] -> ctx bf16 (RNE) [b][t][h*64+d]
__global__ __launch_bounds__(256)
void gather_kernel(const unsigned short* __restrict__ V, const float* __restrict__ w,
                   const int* __restrict__ delays, unsigned short* __restrict__ ctxh)
{
  const int bh = blockIdx.x;
  const int b = bh >> 3, h = bh & 7;
  const int t0 = blockIdx.y * 16;
  __shared__ float ws[TOPK];
  __shared__ int   dls[TOPK];
  const int tid = threadIdx.x;
  if (tid < TOPK) { ws[tid] = w[bh * TOPK + tid]; dls[tid] = delays[bh * TOPK + tid]; }
  __syncthreads();
  const int t  = t0 + (tid >> 4);
  const int d4 = (tid & 15) * 4;
  const unsigned short* Vh = V + (size_t)bh * L_ * DK_;
  float ax = 0.f, ay = 0.f, az = 0.f, aw = 0.f;
#pragma unroll
  for (int j = 0; j < TOPK; j++) {
    int row = (t - dls[j]) & (L_ - 1);
    ushort4 vv = *(const ushort4*)(Vh + (size_t)row * DK_ + d4);
    float wj = ws[j];
    ax += wj * bf2f(vv.x); ay += wj * bf2f(vv.y);
    az += wj * bf2f(vv.z); aw += wj * bf2f(vv.w);
  }
  ushort4 h4;
  h4.x = f2bf_rne(ax); h4.y = f2bf_rne(ay);
  h4.z = f2bf_rne(az); h4.w = f2bf_rne(aw);
  *(ushort4*)(ctxh + ((size_t)(b * L_ + t) * DM_) + h * DK_ + d4) = h4;
}

// ============================ launch ========================================
extern "C" void kernel_launch(void* const* d_in, const int* in_sizes, int n_in,
                              void* d_out, int out_size, void* d_ws, size_t ws_size,
                              hipStream_t stream)
{
  const float* x  = (const float*)d_in[0];
  const float* Wq = (const float*)d_in[1];
  const float* bq = (const float*)d_in[2];
  const float* Wk = (const float*)d_in[3];
  const float* bk = (const float*)d_in[4];
  const float* Wv = (const float*)d_in[5];
  const float* bv = (const float*)d_in[6];
  const float* Wo = (const float*)d_in[7];
  const float* bo = (const float*)d_in[8];
  float* out = (float*)d_out;
  float* ws  = (float*)d_ws;

  // workspace (float offsets). Peak ~88 MB.
  // region0 [0, 8388608): xh (split_all..qkv), then P (fft partials, 32 MB),
  //                       then ctxh [0, 4194304) (gather..o_gemm)
  unsigned short* xh = (unsigned short*)ws;                 // 8.4M bf16
  float* P  = ws;                                           // 8,388,608 f
  unsigned short* ctxh = (unsigned short*)ws;               // 8.4M bf16
  unsigned short* Qb = (unsigned short*)(ws + 8388608);     // 8.4M bf16 [b][h][d][t]
  unsigned short* Kb = (unsigned short*)(ws + 12582912);    // 8.4M bf16 [b][h][d][t]
  unsigned short* Vv = (unsigned short*)(ws + 16777216);    // 8.4M bf16 [b][h][t][d]
  unsigned short* Wqkvh = (unsigned short*)(ws + 20971520); // 786,432 bf16
  unsigned short* Wqkvl = (unsigned short*)(ws + 21364736); // 786,432 bf16
  unsigned short* Woh   = (unsigned short*)(ws + 21757952); // 262,144 bf16
  unsigned short* Wol   = (unsigned short*)(ws + 21889024); // 262,144 bf16
  float* wbuf = ws + 22020096;                              // 512
  int*   dbuf = (int*)(ws + 22020608);                      // 512

  split_all<<<9216, 256, 0, stream>>>(x, Wq, Wk, Wv, Wo, xh, Wqkvh, Wqkvl, Woh, Wol);

  qkv_gemm<<<dim3(MTOT / 128, 12), 256, 0, stream>>>(xh, Wqkvh, Wqkvl,
                                                     bq, bk, bv, Qb, Kb, Vv);

  fft_fwd_kernel<<<dim3(32, 32), 256, 0, stream>>>(Qb, Kb, P);
  fft_inv_topk_kernel<<<32, 256, 0, stream>>>(P, wbuf, dbuf);
  gather_kernel<<<dim3(32, L_ / 16), 256, 0, stream>>>(Vv, wbuf, dbuf, ctxh);

  o_gemm<<<dim3(MTOT / 128, DM_ / 128), 256, 0, stream>>>(ctxh, Woh, Wol, bo, out);
}

// Round 6
// 254.324 us; speedup vs baseline: 1.2572x; 1.2572x over previous
//
#include <hip/hip_runtime.h>
#include <math.h>

#define L_   4096
#define DM_  512
#define B_   4
#define H_   8
#define DK_  64
#define MTOT (B_*L_)      // 16384
#define TOPK 16

typedef __bf16 bf16x8 __attribute__((ext_vector_type(8)));
typedef float  f32x4  __attribute__((ext_vector_type(4)));

// ---------------------------------------------------------------- helpers ---
__device__ __forceinline__ void splitf(float x, unsigned short& h, unsigned short& l) {
  unsigned int u = __float_as_uint(x);
  h = (unsigned short)(u >> 16);                       // truncated hi
  float hf = __uint_as_float(u & 0xFFFF0000u);
  l = (unsigned short)(__float_as_uint(x - hf) >> 16); // truncated lo
}
__device__ __forceinline__ unsigned short f2bf_rne(float f) {
  unsigned int u = __float_as_uint(f);
  return (unsigned short)((u + 0x7FFFu + ((u >> 16) & 1u)) >> 16);
}
__device__ __forceinline__ float bf2f(unsigned short u) {
  return __uint_as_float(((unsigned int)u) << 16);
}

// async 16B/lane global->LDS stage of a 128x32 bf16 tile from a row-major
// source with row stride 512 elements. LDS layout: [128][32] contiguous.
__device__ __forceinline__ void stage_tile_async(const unsigned short* __restrict__ g,
                                                 int row0, int k0,
                                                 unsigned short* lds, int tid) {
  const int wave = tid >> 6;
#pragma unroll
  for (int it = 0; it < 2; ++it) {
    int slot = it * 256 + tid;          // 0..511
    int row  = slot >> 2;               // 0..127
    int ch   = slot & 3;                // 16B chunk within 64B row
    const unsigned short* gp = g + (size_t)(row0 + row) * 512 + k0 + ch * 8;
    unsigned short* lp = lds + (size_t)(it * 256 + wave * 64) * 8;  // wave-uniform base
    __builtin_amdgcn_global_load_lds(
        (const __attribute__((address_space(1))) unsigned int*)gp,
        (__attribute__((address_space(3))) unsigned int*)lp, 16, 0, 0);
  }
}

// =============== fused QKV GEMM: [Q|K|V] = x @ [Wq|Wk|Wv]^T + b =============
// M=16384, N=1536 (3 segs of 512), K=512. 128x128 tile, BK=32, 4 waves.
// 2-pass: Ah*(Bh) + Ah*(Bl); A = x in bf16 (RNE), B split exactly.
__global__ __launch_bounds__(256)
void qkv_gemm(const unsigned short* __restrict__ xh,
              const unsigned short* __restrict__ Wh, const unsigned short* __restrict__ Wl,
              const float* __restrict__ bq, const float* __restrict__ bk,
              const float* __restrict__ bv,
              unsigned short* __restrict__ Qb, unsigned short* __restrict__ Kb,
              unsigned short* __restrict__ Vv)
{
  __shared__ __attribute__((aligned(16))) unsigned short AhS[128 * 32];
  __shared__ __attribute__((aligned(16))) unsigned short BhS[128 * 32];
  __shared__ __attribute__((aligned(16))) unsigned short BlS[128 * 32];

  const int tid  = threadIdx.x;
  const int lane = tid & 63, wave = tid >> 6;
  const int m0 = blockIdx.x * 128, n0 = blockIdx.y * 128;
  const int wm = (wave >> 1) * 64, wn = (wave & 1) * 64;
  const int fr = lane & 15, fq = lane >> 4;

  f32x4 acc[4][4];
#pragma unroll
  for (int i = 0; i < 4; i++)
#pragma unroll
    for (int j = 0; j < 4; j++) acc[i][j] = (f32x4){0.f, 0.f, 0.f, 0.f};

  for (int k0 = 0; k0 < 512; k0 += 32) {
    stage_tile_async(xh, m0, k0, AhS, tid);
    stage_tile_async(Wh, n0, k0, BhS, tid);
    stage_tile_async(Wl, n0, k0, BlS, tid);
    __syncthreads();

    bf16x8 ah[4], bh[4], bl[4];
#pragma unroll
    for (int t = 0; t < 4; ++t) {
      ah[t] = *(const bf16x8*)&AhS[(wm + t * 16 + fr) * 32 + fq * 8];
      bh[t] = *(const bf16x8*)&BhS[(wn + t * 16 + fr) * 32 + fq * 8];
      bl[t] = *(const bf16x8*)&BlS[(wn + t * 16 + fr) * 32 + fq * 8];
    }
#pragma unroll
    for (int mt = 0; mt < 4; ++mt)
#pragma unroll
      for (int nt = 0; nt < 4; ++nt) {
        acc[mt][nt] = __builtin_amdgcn_mfma_f32_16x16x32_bf16(ah[mt], bh[nt], acc[mt][nt], 0, 0, 0);
        acc[mt][nt] = __builtin_amdgcn_mfma_f32_16x16x32_bf16(ah[mt], bl[nt], acc[mt][nt], 0, 0, 0);
      }
    __syncthreads();
  }

  const int seg = (int)(blockIdx.y >> 2);   // 0:Q 1:K 2:V (block-uniform)
  const float* bias = (seg == 0) ? bq : (seg == 1) ? bk : bv;
  const int nseg0 = seg * 512;
  unsigned short* QKdst = (seg == 0) ? Qb : Kb;

#pragma unroll
  for (int nt = 0; nt < 4; ++nt) {
    const int n  = n0 + wn + nt * 16 + fr;
    const int nl = n - nseg0;
    const float bb = bias[nl];
    const int h = nl >> 6, d = nl & 63;
#pragma unroll
    for (int mt = 0; mt < 4; ++mt) {
      const int mb = m0 + wm + mt * 16 + fq * 4;
      f32x4 a = acc[mt][nt];
      if (seg < 2) {
        const int b = mb >> 12, l0 = mb & (L_ - 1);
        ushort4 st;
        st.x = f2bf_rne(a[0] + bb); st.y = f2bf_rne(a[1] + bb);
        st.z = f2bf_rne(a[2] + bb); st.w = f2bf_rne(a[3] + bb);
        *(ushort4*)(QKdst + ((size_t)(b * H_ + h) * DK_ + d) * L_ + l0) = st;
      } else {
#pragma unroll
        for (int r = 0; r < 4; ++r) {
          int m = mb + r;
          int b = m >> 12, l = m & (L_ - 1);
          Vv[((size_t)(b * H_ + h) * L_ + l) * DK_ + d] = f2bf_rne(a[r] + bb);
        }
      }
    }
  }
}

// ====================== O GEMM: out = ctx @ Wo^T + bias =====================
__global__ __launch_bounds__(256)
void o_gemm(const unsigned short* __restrict__ Ah,
            const unsigned short* __restrict__ Bh, const unsigned short* __restrict__ Bl,
            const float* __restrict__ bias, float* __restrict__ Cout)
{
  __shared__ __attribute__((aligned(16))) unsigned short AhS[128 * 32];
  __shared__ __attribute__((aligned(16))) unsigned short BhS[128 * 32];
  __shared__ __attribute__((aligned(16))) unsigned short BlS[128 * 32];

  const int tid  = threadIdx.x;
  const int lane = tid & 63, wave = tid >> 6;
  const int m0 = blockIdx.x * 128, n0 = blockIdx.y * 128;
  const int wm = (wave >> 1) * 64, wn = (wave & 1) * 64;
  const int fr = lane & 15, fq = lane >> 4;

  f32x4 acc[4][4];
#pragma unroll
  for (int i = 0; i < 4; i++)
#pragma unroll
    for (int j = 0; j < 4; j++) acc[i][j] = (f32x4){0.f, 0.f, 0.f, 0.f};

  for (int k0 = 0; k0 < 512; k0 += 32) {
    stage_tile_async(Ah, m0, k0, AhS, tid);
    stage_tile_async(Bh, n0, k0, BhS, tid);
    stage_tile_async(Bl, n0, k0, BlS, tid);
    __syncthreads();

    bf16x8 ah[4], bh[4], bl[4];
#pragma unroll
    for (int t = 0; t < 4; ++t) {
      ah[t] = *(const bf16x8*)&AhS[(wm + t * 16 + fr) * 32 + fq * 8];
      bh[t] = *(const bf16x8*)&BhS[(wn + t * 16 + fr) * 32 + fq * 8];
      bl[t] = *(const bf16x8*)&BlS[(wn + t * 16 + fr) * 32 + fq * 8];
    }
#pragma unroll
    for (int mt = 0; mt < 4; ++mt)
#pragma unroll
      for (int nt = 0; nt < 4; ++nt) {
        acc[mt][nt] = __builtin_amdgcn_mfma_f32_16x16x32_bf16(ah[mt], bh[nt], acc[mt][nt], 0, 0, 0);
        acc[mt][nt] = __builtin_amdgcn_mfma_f32_16x16x32_bf16(ah[mt], bl[nt], acc[mt][nt], 0, 0, 0);
      }
    __syncthreads();
  }

#pragma unroll
  for (int nt = 0; nt < 4; ++nt) {
    const int n = n0 + wn + nt * 16 + fr;
    const float bb = bias[n];
#pragma unroll
    for (int mt = 0; mt < 4; ++mt) {
      const int mb = m0 + wm + mt * 16 + fq * 4;
      f32x4 a = acc[mt][nt];
#pragma unroll
      for (int r = 0; r < 4; ++r) {
        int m = mb + r;
        Cout[(size_t)m * DM_ + n] = a[r] + bb;
      }
    }
  }
}

// ============== one-shot: x -> bf16 (RNE); 4 weights -> hi/lo split =========
__global__ __launch_bounds__(256)
void split_all(const float* __restrict__ x,  const float* __restrict__ Wq,
               const float* __restrict__ Wk, const float* __restrict__ Wv,
               const float* __restrict__ Wo,
               unsigned short* __restrict__ xh,
               unsigned short* __restrict__ Wqkvh, unsigned short* __restrict__ Wqkvl,
               unsigned short* __restrict__ Woh,   unsigned short* __restrict__ Wol)
{
  int i = blockIdx.x * 256 + threadIdx.x;
  if (i < 2097152) {
    float4 v = ((const float4*)x)[i];
    ushort4 h;
    h.x = f2bf_rne(v.x); h.y = f2bf_rne(v.y);
    h.z = f2bf_rne(v.z); h.w = f2bf_rne(v.w);
    ((ushort4*)xh)[i] = h;
    return;
  }
  int j = i - 2097152; int seg = j >> 16; int off = j & 65535;
  const float* src; unsigned short* dh; unsigned short* dl;
  if (seg == 0)      { src = Wq; dh = Wqkvh;          dl = Wqkvl; }
  else if (seg == 1) { src = Wk; dh = Wqkvh + 262144; dl = Wqkvl + 262144; }
  else if (seg == 2) { src = Wv; dh = Wqkvh + 524288; dl = Wqkvl + 524288; }
  else               { src = Wo; dh = Woh;            dl = Wol; }
  float4 v = ((const float4*)src)[off];
  ushort4 h, l;
  splitf(v.x, h.x, l.x); splitf(v.y, h.y, l.y);
  splitf(v.z, h.z, l.z); splitf(v.w, h.w, l.w);
  ((ushort4*)dh)[off] = h;
  ((ushort4*)dl)[off] = l;
}

// ==================== FFT: radix-16 Stockham, N=4096, 3 stages ==============
#define FPAD(a) ((a) + ((a) >> 4))
#define LDSN 4352

__device__ __forceinline__ float2 cmul(float2 a, float2 b) {
  return make_float2(a.x * b.x - a.y * b.y, a.x * b.y + a.y * b.x);
}

__device__ __forceinline__ void dft16(float2* x)
{
  const float C1 = 0.9238795325112867f, S1 = 0.3826834323650898f;
  const float C2 = 0.7071067811865476f;
  const float2 w16[16] = {
    { 1.f, 0.f}, { C1,-S1}, { C2,-C2}, { S1,-C1},
    { 0.f,-1.f}, {-S1,-C1}, {-C2,-C2}, {-C1,-S1},
    {-1.f, 0.f}, {-C1, S1}, {-C2, C2}, {-S1, C1},
    { 0.f, 1.f}, { S1, C1}, { C2, C2}, { C1, S1}};
  float2 y[16];
#pragma unroll
  for (int jj = 0; jj < 4; jj++) {
    float2 a = x[jj], b = x[jj + 4], c = x[jj + 8], d = x[jj + 12];
    float2 t0 = make_float2(a.x + c.x, a.y + c.y);
    float2 t1 = make_float2(a.x - c.x, a.y - c.y);
    float2 t2 = make_float2(b.x + d.x, b.y + d.y);
    float2 t3 = make_float2(b.x - d.x, b.y - d.y);
    float2 u0 = make_float2(t0.x + t2.x, t0.y + t2.y);
    float2 u2 = make_float2(t0.x - t2.x, t0.y - t2.y);
    float2 u1 = make_float2(t1.x + t3.y, t1.y - t3.x);
    float2 u3 = make_float2(t1.x - t3.y, t1.y + t3.x);
    y[4 * jj + 0] = u0;
    y[4 * jj + 1] = cmul(u1, w16[(jj * 1) & 15]);
    y[4 * jj + 2] = cmul(u2, w16[(jj * 2) & 15]);
    y[4 * jj + 3] = cmul(u3, w16[(jj * 3) & 15]);
  }
#pragma unroll
  for (int jj = 0; jj < 4; jj++) {
    float2 a = y[jj], b = y[jj + 4], c = y[jj + 8], d = y[jj + 12];
    float2 t0 = make_float2(a.x + c.x, a.y + c.y);
    float2 t1 = make_float2(a.x - c.x, a.y - c.y);
    float2 t2 = make_float2(b.x + d.x, b.y + d.y);
    float2 t3 = make_float2(b.x - d.x, b.y - d.y);
    x[jj + 0]  = make_float2(t0.x + t2.x, t0.y + t2.y);
    x[jj + 8]  = make_float2(t0.x - t2.x, t0.y - t2.y);
    x[jj + 4]  = make_float2(t1.x + t3.y, t1.y - t3.x);
    x[jj + 12] = make_float2(t1.x - t3.y, t1.y + t3.x);
  }
}

// stage 1 from registers: x[r] = z[j + 256r]; writes padded stage-1 output.
__device__ __forceinline__ void fft_stage1_reg(float2* x, float2* __restrict__ Ys, int j)
{
  dft16(x);
  float ang = -1.5339807878856412e-3f * (float)j;   // -2*pi/4096 * j
  float2 w; __sincosf(ang, &w.y, &w.x);
  float2 t = w;
#pragma unroll
  for (int k = 1; k < 16; k++) { x[k] = cmul(x[k], t); t = cmul(t, w); }
  float2* yp = Ys + 17 * j;                         // FPAD(16j+k) = 17j+k
#pragma unroll
  for (int k = 0; k < 16; k++) yp[k] = x[k];
}

template<int S, bool PADOUT>
__device__ __forceinline__ void fft_stage(const float2* __restrict__ Xs,
                                          float2* __restrict__ Ys, int j)
{
  float2 x[16];
#pragma unroll
  for (int r = 0; r < 16; r++) { int a = j + 256 * r; x[r] = Xs[FPAD(a)]; }
  dft16(x);
  if (S < 256) {
    int p = (S == 1) ? j : (j >> 4);
    float ang = -1.5339807878856412e-3f * (float)(p * S);
    float2 w; __sincosf(ang, &w.y, &w.x);
    float2 t = w;
#pragma unroll
    for (int k = 1; k < 16; k++) { x[k] = cmul(x[k], t); t = cmul(t, w); }
  }
  const int q = j & (S - 1);
  const int base = q + ((j - q) << 4);   // q + 16*p*S
#pragma unroll
  for (int k = 0; k < 16; k++) {
    int a = base + k * S;
    Ys[PADOUT ? FPAD(a) : a] = x[k];
  }
}

// One workgroup per (b*H+h, d-group of 2). grid (32, 32). Q,K in bf16.
__global__ __launch_bounds__(256)
void fft_fwd_kernel(const unsigned short* __restrict__ Qb,
                    const unsigned short* __restrict__ Kb,
                    float* __restrict__ P)
{
  __shared__ __attribute__((aligned(16))) float2 Abuf[LDSN];
  __shared__ __attribute__((aligned(16))) float2 Bbuf[LDSN];
  const int tid = threadIdx.x;
  const int bh = blockIdx.x;      // 0..31
  const int g  = blockIdx.y;      // 0..31
  float2 accv[16];
#pragma unroll
  for (int r = 0; r < 16; r++) accv[r] = make_float2(0.f, 0.f);

  for (int dd = 0; dd < 2; dd++) {
    int d = g * 2 + dd;
    const unsigned short* q = Qb + ((size_t)bh * DK_ + d) * L_;
    const unsigned short* k = Kb + ((size_t)bh * DK_ + d) * L_;
    float2 x[16];
#pragma unroll
    for (int r = 0; r < 16; r++) {
      int t = tid + 256 * r;
      x[r] = make_float2(bf2f(q[t]), bf2f(k[t]));   // z = q + i*k
    }
    __syncthreads();               // prev channel's unpack reads of Abuf done
    fft_stage1_reg(x, Abuf, tid);
    __syncthreads();
    fft_stage<16, true>(Abuf, Bbuf, tid);
    __syncthreads();
    fft_stage<256, false>(Bbuf, Abuf, tid);   // result in Abuf, unpadded
    __syncthreads();
#pragma unroll
    for (int r = 0; r < 16; r++) {
      int f = tid + 256 * r;
      float2 zf = Abuf[f];
      float2 zc = Abuf[(L_ - f) & (L_ - 1)];
      float qr = 0.5f * (zf.x + zc.x);       // Qf = (Z[f]+conj(Z[N-f]))/2
      float qi = 0.5f * (zf.y - zc.y);
      float kr = 0.5f * (zf.y + zc.y);       // Kf = (Z[f]-conj(Z[N-f]))/(2i)
      float ki = 0.5f * (zc.x - zf.x);
      accv[r].x += qr * kr + qi * ki;        // G = Qf * conj(Kf)
      accv[r].y += qi * kr - qr * ki;
    }
  }
  float2* Pp = (float2*)P + ((size_t)bh * 32 + g) * L_;
#pragma unroll
  for (int r = 0; r < 16; r++) Pp[tid + 256 * r] = accv[r];
}

// ====== reduce 32 partial spectra -> conjugated spectrum S (HBM stream) =====
// grid (32, 8), 256 thr. Each thread sums one float4 chunk (2 complex) over
// all 32 partials. Same summation order as before -> bit-identical.
__global__ __launch_bounds__(256)
void reduce_partials(const float* __restrict__ P, float* __restrict__ S)
{
  const int bh = blockIdx.x;
  const int c  = blockIdx.y * 256 + threadIdx.x;   // 0..2047 float4 chunks
  const float4* Pp4 = (const float4*)P + (size_t)bh * 32 * 2048 + c;
  float4 s = make_float4(0.f, 0.f, 0.f, 0.f);
#pragma unroll
  for (int g = 0; g < 32; g++) {
    float4 v = Pp4[(size_t)g * 2048];
    s.x += v.x; s.y += v.y; s.z += v.z; s.w += v.w;
  }
  ((float4*)S)[(size_t)bh * 2048 + c] = make_float4(s.x, -s.y, s.z, -s.w);  // conj
}

// ================= fused: inverse FFT of S + top-16 + softmax ===============
__global__ __launch_bounds__(256)
void fft_inv_topk_kernel(const float* __restrict__ S, float* __restrict__ w,
                         int* __restrict__ delays)
{
  __shared__ __attribute__((aligned(16))) float2 Abuf[LDSN];
  __shared__ __attribute__((aligned(16))) float2 Bbuf[LDSN];
  __shared__ float swv[4];
  __shared__ int   swi[4];
  __shared__ float topv[TOPK];
  __shared__ int   topi[TOPK];
  __shared__ int   winner;
  const int tid = threadIdx.x;
  const int bh = blockIdx.x;
  const float2* Sp = (const float2*)S + (size_t)bh * L_;

  float2 x[16];
#pragma unroll
  for (int r = 0; r < 16; r++) x[r] = Sp[tid + 256 * r];
  fft_stage1_reg(x, Abuf, tid);
  __syncthreads();
  fft_stage<16, true>(Abuf, Bbuf, tid);
  __syncthreads();
  fft_stage<256, false>(Bbuf, Abuf, tid);   // result in Abuf, unpadded
  __syncthreads();

  const float scale = 1.0f / ((float)L_ * (float)DK_);
  float v[16];
#pragma unroll
  for (int r = 0; r < 16; r++) v[r] = Abuf[tid + 256 * r].x * scale;

  for (int it = 0; it < TOPK; it++) {
    float bv = -INFINITY; int bi = 0;
#pragma unroll
    for (int r = 0; r < 16; r++) {
      if (v[r] > bv) { bv = v[r]; bi = tid + 256 * r; }
    }
#pragma unroll
    for (int off = 32; off > 0; off >>= 1) {
      float ov = __shfl_down(bv, off, 64);
      int   oi = __shfl_down(bi, off, 64);
      if (ov > bv || (ov == bv && oi < bi)) { bv = ov; bi = oi; }
    }
    if ((tid & 63) == 0) { swv[tid >> 6] = bv; swi[tid >> 6] = bi; }
    __syncthreads();
    if (tid == 0) {
      float mv = swv[0]; int mi = swi[0];
#pragma unroll
      for (int q = 1; q < 4; q++)
        if (swv[q] > mv || (swv[q] == mv && swi[q] < mi)) { mv = swv[q]; mi = swi[q]; }
      topv[it] = mv; topi[it] = mi; winner = mi;
    }
    __syncthreads();
    int win = winner;
    if ((win & 255) == tid) v[win >> 8] = -INFINITY;
  }
  if (tid == 0) {
    float mx = topv[0];
    for (int j = 1; j < TOPK; j++) mx = fmaxf(mx, topv[j]);
    float e[TOPK]; float se = 0.f;
    for (int j = 0; j < TOPK; j++) { e[j] = expf(topv[j] - mx); se += e[j]; }
    float inv = 1.0f / se;
    for (int j = 0; j < TOPK; j++) {
      w[bh * TOPK + j] = e[j] * inv;
      delays[bh * TOPK + j] = topi[j];
    }
  }
}

// ============================ delay gather ==================================
// V bf16 [b][h][t][d] -> ctx bf16 (RNE) [b][t][h*64+d]
__global__ __launch_bounds__(256)
void gather_kernel(const unsigned short* __restrict__ V, const float* __restrict__ w,
                   const int* __restrict__ delays, unsigned short* __restrict__ ctxh)
{
  const int bh = blockIdx.x;
  const int b = bh >> 3, h = bh & 7;
  const int t0 = blockIdx.y * 16;
  __shared__ float ws[TOPK];
  __shared__ int   dls[TOPK];
  const int tid = threadIdx.x;
  if (tid < TOPK) { ws[tid] = w[bh * TOPK + tid]; dls[tid] = delays[bh * TOPK + tid]; }
  __syncthreads();
  const int t  = t0 + (tid >> 4);
  const int d4 = (tid & 15) * 4;
  const unsigned short* Vh = V + (size_t)bh * L_ * DK_;
  float ax = 0.f, ay = 0.f, az = 0.f, aw = 0.f;
#pragma unroll
  for (int j = 0; j < TOPK; j++) {
    int row = (t - dls[j]) & (L_ - 1);
    ushort4 vv = *(const ushort4*)(Vh + (size_t)row * DK_ + d4);
    float wj = ws[j];
    ax += wj * bf2f(vv.x); ay += wj * bf2f(vv.y);
    az += wj * bf2f(vv.z); aw += wj * bf2f(vv.w);
  }
  ushort4 h4;
  h4.x = f2bf_rne(ax); h4.y = f2bf_rne(ay);
  h4.z = f2bf_rne(az); h4.w = f2bf_rne(aw);
  *(ushort4*)(ctxh + ((size_t)(b * L_ + t) * DM_) + h * DK_ + d4) = h4;
}

// ============================ launch ========================================
extern "C" void kernel_launch(void* const* d_in, const int* in_sizes, int n_in,
                              void* d_out, int out_size, void* d_ws, size_t ws_size,
                              hipStream_t stream)
{
  const float* x  = (const float*)d_in[0];
  const float* Wq = (const float*)d_in[1];
  const float* bq = (const float*)d_in[2];
  const float* Wk = (const float*)d_in[3];
  const float* bk = (const float*)d_in[4];
  const float* Wv = (const float*)d_in[5];
  const float* bv = (const float*)d_in[6];
  const float* Wo = (const float*)d_in[7];
  const float* bo = (const float*)d_in[8];
  float* out = (float*)d_out;
  float* ws  = (float*)d_ws;

  // workspace (float offsets). Peak ~90 MB.
  // region0 [0, 8388608): xh (split..qkv), then P (fft partials, 32 MB),
  //                       then ctxh [0, 4194304) (gather..o_gemm)
  unsigned short* xh = (unsigned short*)ws;                 // 8.4M bf16
  float* P  = ws;                                           // 8,388,608 f
  unsigned short* ctxh = (unsigned short*)ws;               // 8.4M bf16
  unsigned short* Qb = (unsigned short*)(ws + 8388608);     // 8.4M bf16 [b][h][d][t]
  unsigned short* Kb = (unsigned short*)(ws + 12582912);    // 8.4M bf16 [b][h][d][t]
  unsigned short* Vv = (unsigned short*)(ws + 16777216);    // 8.4M bf16 [b][h][t][d]
  unsigned short* Wqkvh = (unsigned short*)(ws + 20971520); // 786,432 bf16
  unsigned short* Wqkvl = (unsigned short*)(ws + 21364736); // 786,432 bf16
  unsigned short* Woh   = (unsigned short*)(ws + 21757952); // 262,144 bf16
  unsigned short* Wol   = (unsigned short*)(ws + 21889024); // 262,144 bf16
  float* wbuf = ws + 22020096;                              // 512
  int*   dbuf = (int*)(ws + 22020608);                      // 512
  float* S    = ws + 22021120;                              // 262,144 f (1 MB)

  split_all<<<9216, 256, 0, stream>>>(x, Wq, Wk, Wv, Wo, xh, Wqkvh, Wqkvl, Woh, Wol);

  qkv_gemm<<<dim3(MTOT / 128, 12), 256, 0, stream>>>(xh, Wqkvh, Wqkvl,
                                                     bq, bk, bv, Qb, Kb, Vv);

  fft_fwd_kernel<<<dim3(32, 32), 256, 0, stream>>>(Qb, Kb, P);
  reduce_partials<<<dim3(32, 8), 256, 0, stream>>>(P, S);
  fft_inv_topk_kernel<<<32, 256, 0, stream>>>(S, wbuf, dbuf);
  gather_kernel<<<dim3(32, L_ / 16), 256, 0, stream>>>(Vv, wbuf, dbuf, ctxh);

  o_gemm<<<dim3(MTOT / 128, DM_ / 128), 256, 0, stream>>>(ctxh, Woh, Wol, bo, out);
}

// Round 7
// 230.220 us; speedup vs baseline: 1.3888x; 1.1047x over previous
//
#include <hip/hip_runtime.h>
#include <math.h>

#define L_   4096
#define DM_  512
#define B_   4
#define H_   8
#define DK_  64
#define MTOT (B_*L_)      // 16384
#define TOPK 16

typedef _Float16 f16x8 __attribute__((ext_vector_type(8)));
typedef float    f32x4 __attribute__((ext_vector_type(4)));

// ---------------------------------------------------------------- helpers ---
__device__ __forceinline__ float h2f(unsigned short u) {
  _Float16 h; __builtin_memcpy(&h, &u, 2); return (float)h;
}
__device__ __forceinline__ unsigned short f2h(float f) {
  _Float16 h = (_Float16)f;   // RNE
  unsigned short u; __builtin_memcpy(&u, &h, 2); return u;
}

// async 16B/lane global->LDS stage of a 128x32 fp16 tile from a row-major
// source with row stride 512 elements. LDS layout: [128][32] contiguous.
__device__ __forceinline__ void stage_tile_async(const unsigned short* __restrict__ g,
                                                 int row0, int k0,
                                                 unsigned short* lds, int tid) {
  const int wave = tid >> 6;
#pragma unroll
  for (int it = 0; it < 2; ++it) {
    int slot = it * 256 + tid;          // 0..511
    int row  = slot >> 2;               // 0..127
    int ch   = slot & 3;                // 16B chunk within 64B row
    const unsigned short* gp = g + (size_t)(row0 + row) * 512 + k0 + ch * 8;
    unsigned short* lp = lds + (size_t)(it * 256 + wave * 64) * 8;  // wave-uniform base
    __builtin_amdgcn_global_load_lds(
        (const __attribute__((address_space(1))) unsigned int*)gp,
        (__attribute__((address_space(3))) unsigned int*)lp, 16, 0, 0);
  }
}

// =============== fused QKV GEMM: [Q|K|V] = x @ [Wq|Wk|Wv]^T + b =============
// M=16384, N=1536 (3 segs of 512), K=512. 128x128 tile, BK=32, 4 waves.
// Single-pass fp16 (RNE inputs, fp32 accumulate).
// seg 0 -> Qh fp16 [b][h][d][t]; seg 1 -> Kh fp16 [b][h][d][t];
// seg 2 -> Vv fp16 [b][h][t][d].
__global__ __launch_bounds__(256)
void qkv_gemm(const unsigned short* __restrict__ xh,
              const unsigned short* __restrict__ Wh,
              const float* __restrict__ bq, const float* __restrict__ bk,
              const float* __restrict__ bv,
              unsigned short* __restrict__ Qh, unsigned short* __restrict__ Kh,
              unsigned short* __restrict__ Vv)
{
  __shared__ __attribute__((aligned(16))) unsigned short AhS[128 * 32];
  __shared__ __attribute__((aligned(16))) unsigned short BhS[128 * 32];

  const int tid  = threadIdx.x;
  const int lane = tid & 63, wave = tid >> 6;
  const int m0 = blockIdx.x * 128, n0 = blockIdx.y * 128;
  const int wm = (wave >> 1) * 64, wn = (wave & 1) * 64;
  const int fr = lane & 15, fq = lane >> 4;

  f32x4 acc[4][4];
#pragma unroll
  for (int i = 0; i < 4; i++)
#pragma unroll
    for (int j = 0; j < 4; j++) acc[i][j] = (f32x4){0.f, 0.f, 0.f, 0.f};

  for (int k0 = 0; k0 < 512; k0 += 32) {
    stage_tile_async(xh, m0, k0, AhS, tid);
    stage_tile_async(Wh, n0, k0, BhS, tid);
    __syncthreads();

    f16x8 ah[4], bh[4];
#pragma unroll
    for (int t = 0; t < 4; ++t) {
      ah[t] = *(const f16x8*)&AhS[(wm + t * 16 + fr) * 32 + fq * 8];
      bh[t] = *(const f16x8*)&BhS[(wn + t * 16 + fr) * 32 + fq * 8];
    }
#pragma unroll
    for (int mt = 0; mt < 4; ++mt)
#pragma unroll
      for (int nt = 0; nt < 4; ++nt)
        acc[mt][nt] = __builtin_amdgcn_mfma_f32_16x16x32_f16(ah[mt], bh[nt], acc[mt][nt], 0, 0, 0);
    __syncthreads();
  }

  const int seg = (int)(blockIdx.y >> 2);   // 0:Q 1:K 2:V (block-uniform)
  const float* bias = (seg == 0) ? bq : (seg == 1) ? bk : bv;
  const int nseg0 = seg * 512;
  unsigned short* QKdst = (seg == 0) ? Qh : Kh;

#pragma unroll
  for (int nt = 0; nt < 4; ++nt) {
    const int n  = n0 + wn + nt * 16 + fr;
    const int nl = n - nseg0;
    const float bb = bias[nl];
    const int h = nl >> 6, d = nl & 63;
#pragma unroll
    for (int mt = 0; mt < 4; ++mt) {
      const int mb = m0 + wm + mt * 16 + fq * 4;
      f32x4 a = acc[mt][nt];
      if (seg < 2) {
        const int b = mb >> 12, l0 = mb & (L_ - 1);
        ushort4 st;
        st.x = f2h(a[0] + bb); st.y = f2h(a[1] + bb);
        st.z = f2h(a[2] + bb); st.w = f2h(a[3] + bb);
        *(ushort4*)(QKdst + ((size_t)(b * H_ + h) * DK_ + d) * L_ + l0) = st;
      } else {
#pragma unroll
        for (int r = 0; r < 4; ++r) {
          int m = mb + r;
          int b = m >> 12, l = m & (L_ - 1);
          Vv[((size_t)(b * H_ + h) * L_ + l) * DK_ + d] = f2h(a[r] + bb);
        }
      }
    }
  }
}

// ====================== O GEMM: out = ctx @ Wo^T + bias =====================
__global__ __launch_bounds__(256)
void o_gemm(const unsigned short* __restrict__ Ah,
            const unsigned short* __restrict__ Bh,
            const float* __restrict__ bias, float* __restrict__ Cout)
{
  __shared__ __attribute__((aligned(16))) unsigned short AhS[128 * 32];
  __shared__ __attribute__((aligned(16))) unsigned short BhS[128 * 32];

  const int tid  = threadIdx.x;
  const int lane = tid & 63, wave = tid >> 6;
  const int m0 = blockIdx.x * 128, n0 = blockIdx.y * 128;
  const int wm = (wave >> 1) * 64, wn = (wave & 1) * 64;
  const int fr = lane & 15, fq = lane >> 4;

  f32x4 acc[4][4];
#pragma unroll
  for (int i = 0; i < 4; i++)
#pragma unroll
    for (int j = 0; j < 4; j++) acc[i][j] = (f32x4){0.f, 0.f, 0.f, 0.f};

  for (int k0 = 0; k0 < 512; k0 += 32) {
    stage_tile_async(Ah, m0, k0, AhS, tid);
    stage_tile_async(Bh, n0, k0, BhS, tid);
    __syncthreads();

    f16x8 ah[4], bh[4];
#pragma unroll
    for (int t = 0; t < 4; ++t) {
      ah[t] = *(const f16x8*)&AhS[(wm + t * 16 + fr) * 32 + fq * 8];
      bh[t] = *(const f16x8*)&BhS[(wn + t * 16 + fr) * 32 + fq * 8];
    }
#pragma unroll
    for (int mt = 0; mt < 4; ++mt)
#pragma unroll
      for (int nt = 0; nt < 4; ++nt)
        acc[mt][nt] = __builtin_amdgcn_mfma_f32_16x16x32_f16(ah[mt], bh[nt], acc[mt][nt], 0, 0, 0);
    __syncthreads();
  }

#pragma unroll
  for (int nt = 0; nt < 4; ++nt) {
    const int n = n0 + wn + nt * 16 + fr;
    const float bb = bias[n];
#pragma unroll
    for (int mt = 0; mt < 4; ++mt) {
      const int mb = m0 + wm + mt * 16 + fq * 4;
      f32x4 a = acc[mt][nt];
#pragma unroll
      for (int r = 0; r < 4; ++r) {
        int m = mb + r;
        Cout[(size_t)m * DM_ + n] = a[r] + bb;
      }
    }
  }
}

// ============== one-shot: x and all 4 weights -> fp16 (RNE) =================
// chunks: x = 2,097,152 float4; each W = 65,536 float4. total 2,359,296.
__global__ __launch_bounds__(256)
void split_all(const float* __restrict__ x,  const float* __restrict__ Wq,
               const float* __restrict__ Wk, const float* __restrict__ Wv,
               const float* __restrict__ Wo,
               unsigned short* __restrict__ xh,
               unsigned short* __restrict__ Wqkvh, unsigned short* __restrict__ Woh)
{
  int i = blockIdx.x * 256 + threadIdx.x;
  const float* src; unsigned short* dh; int off;
  if (i < 2097152) { src = x; dh = xh; off = i; }
  else {
    int j = i - 2097152; int seg = j >> 16; off = j & 65535;
    if (seg == 0)      { src = Wq; dh = Wqkvh; }
    else if (seg == 1) { src = Wk; dh = Wqkvh + 262144; }
    else if (seg == 2) { src = Wv; dh = Wqkvh + 524288; }
    else               { src = Wo; dh = Woh; }
  }
  float4 v = ((const float4*)src)[off];
  ushort4 h;
  h.x = f2h(v.x); h.y = f2h(v.y); h.z = f2h(v.z); h.w = f2h(v.w);
  ((ushort4*)dh)[off] = h;
}

// ==================== FFT: radix-16 Stockham, N=4096, 3 stages ==============
#define FPAD(a) ((a) + ((a) >> 4))
#define LDSN 4352

__device__ __forceinline__ float2 cmul(float2 a, float2 b) {
  return make_float2(a.x * b.x - a.y * b.y, a.x * b.y + a.y * b.x);
}

__device__ __forceinline__ void dft16(float2* x)
{
  const float C1 = 0.9238795325112867f, S1 = 0.3826834323650898f;
  const float C2 = 0.7071067811865476f;
  const float2 w16[16] = {
    { 1.f, 0.f}, { C1,-S1}, { C2,-C2}, { S1,-C1},
    { 0.f,-1.f}, {-S1,-C1}, {-C2,-C2}, {-C1,-S1},
    {-1.f, 0.f}, {-C1, S1}, {-C2, C2}, {-S1, C1},
    { 0.f, 1.f}, { S1, C1}, { C2, C2}, { C1, S1}};
  float2 y[16];
#pragma unroll
  for (int jj = 0; jj < 4; jj++) {
    float2 a = x[jj], b = x[jj + 4], c = x[jj + 8], d = x[jj + 12];
    float2 t0 = make_float2(a.x + c.x, a.y + c.y);
    float2 t1 = make_float2(a.x - c.x, a.y - c.y);
    float2 t2 = make_float2(b.x + d.x, b.y + d.y);
    float2 t3 = make_float2(b.x - d.x, b.y - d.y);
    float2 u0 = make_float2(t0.x + t2.x, t0.y + t2.y);
    float2 u2 = make_float2(t0.x - t2.x, t0.y - t2.y);
    float2 u1 = make_float2(t1.x + t3.y, t1.y - t3.x);
    float2 u3 = make_float2(t1.x - t3.y, t1.y + t3.x);
    y[4 * jj + 0] = u0;
    y[4 * jj + 1] = cmul(u1, w16[(jj * 1) & 15]);
    y[4 * jj + 2] = cmul(u2, w16[(jj * 2) & 15]);
    y[4 * jj + 3] = cmul(u3, w16[(jj * 3) & 15]);
  }
#pragma unroll
  for (int jj = 0; jj < 4; jj++) {
    float2 a = y[jj], b = y[jj + 4], c = y[jj + 8], d = y[jj + 12];
    float2 t0 = make_float2(a.x + c.x, a.y + c.y);
    float2 t1 = make_float2(a.x - c.x, a.y - c.y);
    float2 t2 = make_float2(b.x + d.x, b.y + d.y);
    float2 t3 = make_float2(b.x - d.x, b.y - d.y);
    x[jj + 0]  = make_float2(t0.x + t2.x, t0.y + t2.y);
    x[jj + 8]  = make_float2(t0.x - t2.x, t0.y - t2.y);
    x[jj + 4]  = make_float2(t1.x + t3.y, t1.y - t3.x);
    x[jj + 12] = make_float2(t1.x - t3.y, t1.y + t3.x);
  }
}

// stage 1 from registers: x[r] = z[j + 256r]; writes padded stage-1 output.
__device__ __forceinline__ void fft_stage1_reg(float2* x, float2* __restrict__ Ys, int j)
{
  dft16(x);
  float ang = -1.5339807878856412e-3f * (float)j;   // -2*pi/4096 * j
  float2 w; __sincosf(ang, &w.y, &w.x);
  float2 t = w;
#pragma unroll
  for (int k = 1; k < 16; k++) { x[k] = cmul(x[k], t); t = cmul(t, w); }
  float2* yp = Ys + 17 * j;                         // FPAD(16j+k) = 17j+k
#pragma unroll
  for (int k = 0; k < 16; k++) yp[k] = x[k];
}

template<int S, bool PADOUT>
__device__ __forceinline__ void fft_stage(const float2* __restrict__ Xs,
                                          float2* __restrict__ Ys, int j)
{
  float2 x[16];
#pragma unroll
  for (int r = 0; r < 16; r++) { int a = j + 256 * r; x[r] = Xs[FPAD(a)]; }
  dft16(x);
  if (S < 256) {
    int p = (S == 1) ? j : (j >> 4);
    float ang = -1.5339807878856412e-3f * (float)(p * S);
    float2 w; __sincosf(ang, &w.y, &w.x);
    float2 t = w;
#pragma unroll
    for (int k = 1; k < 16; k++) { x[k] = cmul(x[k], t); t = cmul(t, w); }
  }
  const int q = j & (S - 1);
  const int base = q + ((j - q) << 4);   // q + 16*p*S
#pragma unroll
  for (int k = 0; k < 16; k++) {
    int a = base + k * S;
    Ys[PADOUT ? FPAD(a) : a] = x[k];
  }
}

// One workgroup per (b*H+h, d-group of 2). grid (32, 32). Q,K in fp16.
__global__ __launch_bounds__(256)
void fft_fwd_kernel(const unsigned short* __restrict__ Qh,
                    const unsigned short* __restrict__ Kh,
                    float* __restrict__ P)
{
  __shared__ __attribute__((aligned(16))) float2 Abuf[LDSN];
  __shared__ __attribute__((aligned(16))) float2 Bbuf[LDSN];
  const int tid = threadIdx.x;
  const int bh = blockIdx.x;      // 0..31
  const int g  = blockIdx.y;      // 0..31
  float2 accv[16];
#pragma unroll
  for (int r = 0; r < 16; r++) accv[r] = make_float2(0.f, 0.f);

  for (int dd = 0; dd < 2; dd++) {
    int d = g * 2 + dd;
    const unsigned short* q = Qh + ((size_t)bh * DK_ + d) * L_;
    const unsigned short* k = Kh + ((size_t)bh * DK_ + d) * L_;
    float2 x[16];
#pragma unroll
    for (int r = 0; r < 16; r++) {
      int t = tid + 256 * r;
      x[r] = make_float2(h2f(q[t]), h2f(k[t]));   // z = q + i*k
    }
    __syncthreads();               // prev channel's unpack reads of Abuf done
    fft_stage1_reg(x, Abuf, tid);
    __syncthreads();
    fft_stage<16, true>(Abuf, Bbuf, tid);
    __syncthreads();
    fft_stage<256, false>(Bbuf, Abuf, tid);   // result in Abuf, unpadded
    __syncthreads();
#pragma unroll
    for (int r = 0; r < 16; r++) {
      int f = tid + 256 * r;
      float2 zf = Abuf[f];
      float2 zc = Abuf[(L_ - f) & (L_ - 1)];
      float qr = 0.5f * (zf.x + zc.x);       // Qf = (Z[f]+conj(Z[N-f]))/2
      float qi = 0.5f * (zf.y - zc.y);
      float kr = 0.5f * (zf.y + zc.y);       // Kf = (Z[f]-conj(Z[N-f]))/(2i)
      float ki = 0.5f * (zc.x - zf.x);
      accv[r].x += qr * kr + qi * ki;        // G = Qf * conj(Kf)
      accv[r].y += qi * kr - qr * ki;
    }
  }
  float2* Pp = (float2*)P + ((size_t)bh * 32 + g) * L_;
#pragma unroll
  for (int r = 0; r < 16; r++) Pp[tid + 256 * r] = accv[r];
}

// ====== reduce 32 partial spectra -> conjugated spectrum S (HBM stream) =====
__global__ __launch_bounds__(256)
void reduce_partials(const float* __restrict__ P, float* __restrict__ S)
{
  const int bh = blockIdx.x;
  const int c  = blockIdx.y * 256 + threadIdx.x;   // 0..2047 float4 chunks
  const float4* Pp4 = (const float4*)P + (size_t)bh * 32 * 2048 + c;
  float4 s = make_float4(0.f, 0.f, 0.f, 0.f);
#pragma unroll
  for (int g = 0; g < 32; g++) {
    float4 v = Pp4[(size_t)g * 2048];
    s.x += v.x; s.y += v.y; s.z += v.z; s.w += v.w;
  }
  ((float4*)S)[(size_t)bh * 2048 + c] = make_float4(s.x, -s.y, s.z, -s.w);  // conj
}

// ================= fused: inverse FFT of S + top-16 + softmax ===============
__global__ __launch_bounds__(256)
void fft_inv_topk_kernel(const float* __restrict__ S, float* __restrict__ w,
                         int* __restrict__ delays)
{
  __shared__ __attribute__((aligned(16))) float2 Abuf[LDSN];
  __shared__ __attribute__((aligned(16))) float2 Bbuf[LDSN];
  __shared__ float swv[4];
  __shared__ int   swi[4];
  __shared__ float topv[TOPK];
  __shared__ int   topi[TOPK];
  __shared__ int   winner;
  const int tid = threadIdx.x;
  const int bh = blockIdx.x;
  const float2* Sp = (const float2*)S + (size_t)bh * L_;

  float2 x[16];
#pragma unroll
  for (int r = 0; r < 16; r++) x[r] = Sp[tid + 256 * r];
  fft_stage1_reg(x, Abuf, tid);
  __syncthreads();
  fft_stage<16, true>(Abuf, Bbuf, tid);
  __syncthreads();
  fft_stage<256, false>(Bbuf, Abuf, tid);   // result in Abuf, unpadded
  __syncthreads();

  const float scale = 1.0f / ((float)L_ * (float)DK_);
  float v[16];
#pragma unroll
  for (int r = 0; r < 16; r++) v[r] = Abuf[tid + 256 * r].x * scale;

  for (int it = 0; it < TOPK; it++) {
    float bv = -INFINITY; int bi = 0;
#pragma unroll
    for (int r = 0; r < 16; r++) {
      if (v[r] > bv) { bv = v[r]; bi = tid + 256 * r; }
    }
#pragma unroll
    for (int off = 32; off > 0; off >>= 1) {
      float ov = __shfl_down(bv, off, 64);
      int   oi = __shfl_down(bi, off, 64);
      if (ov > bv || (ov == bv && oi < bi)) { bv = ov; bi = oi; }
    }
    if ((tid & 63) == 0) { swv[tid >> 6] = bv; swi[tid >> 6] = bi; }
    __syncthreads();
    if (tid == 0) {
      float mv = swv[0]; int mi = swi[0];
#pragma unroll
      for (int q = 1; q < 4; q++)
        if (swv[q] > mv || (swv[q] == mv && swi[q] < mi)) { mv = swv[q]; mi = swi[q]; }
      topv[it] = mv; topi[it] = mi; winner = mi;
    }
    __syncthreads();
    int win = winner;
    if ((win & 255) == tid) v[win >> 8] = -INFINITY;
  }
  if (tid == 0) {
    float mx = topv[0];
    for (int j = 1; j < TOPK; j++) mx = fmaxf(mx, topv[j]);
    float e[TOPK]; float se = 0.f;
    for (int j = 0; j < TOPK; j++) { e[j] = expf(topv[j] - mx); se += e[j]; }
    float inv = 1.0f / se;
    for (int j = 0; j < TOPK; j++) {
      w[bh * TOPK + j] = e[j] * inv;
      delays[bh * TOPK + j] = topi[j];
    }
  }
}

// ============================ delay gather ==================================
// V fp16 [b][h][t][d] -> ctx fp16 (RNE) [b][t][h*64+d]
__global__ __launch_bounds__(256)
void gather_kernel(const unsigned short* __restrict__ V, const float* __restrict__ w,
                   const int* __restrict__ delays, unsigned short* __restrict__ ctxh)
{
  const int bh = blockIdx.x;
  const int b = bh >> 3, h = bh & 7;
  const int t0 = blockIdx.y * 16;
  __shared__ float ws[TOPK];
  __shared__ int   dls[TOPK];
  const int tid = threadIdx.x;
  if (tid < TOPK) { ws[tid] = w[bh * TOPK + tid]; dls[tid] = delays[bh * TOPK + tid]; }
  __syncthreads();
  const int t  = t0 + (tid >> 4);
  const int d4 = (tid & 15) * 4;
  const unsigned short* Vh = V + (size_t)bh * L_ * DK_;
  float ax = 0.f, ay = 0.f, az = 0.f, aw = 0.f;
#pragma unroll
  for (int j = 0; j < TOPK; j++) {
    int row = (t - dls[j]) & (L_ - 1);
    ushort4 vv = *(const ushort4*)(Vh + (size_t)row * DK_ + d4);
    float wj = ws[j];
    ax += wj * h2f(vv.x); ay += wj * h2f(vv.y);
    az += wj * h2f(vv.z); aw += wj * h2f(vv.w);
  }
  ushort4 h4;
  h4.x = f2h(ax); h4.y = f2h(ay); h4.z = f2h(az); h4.w = f2h(aw);
  *(ushort4*)(ctxh + ((size_t)(b * L_ + t) * DM_) + h * DK_ + d4) = h4;
}

// ============================ launch ========================================
extern "C" void kernel_launch(void* const* d_in, const int* in_sizes, int n_in,
                              void* d_out, int out_size, void* d_ws, size_t ws_size,
                              hipStream_t stream)
{
  const float* x  = (const float*)d_in[0];
  const float* Wq = (const float*)d_in[1];
  const float* bq = (const float*)d_in[2];
  const float* Wk = (const float*)d_in[3];
  const float* bk = (const float*)d_in[4];
  const float* Wv = (const float*)d_in[5];
  const float* bv = (const float*)d_in[6];
  const float* Wo = (const float*)d_in[7];
  const float* bo = (const float*)d_in[8];
  float* out = (float*)d_out;
  float* ws  = (float*)d_ws;

  // workspace (float offsets). Peak ~87 MB.
  // region0 [0, 8388608): xh fp16 (split..qkv), then P (fft partials, 32 MB),
  //                       then ctxh fp16 (gather..o_gemm)
  unsigned short* xh = (unsigned short*)ws;                 // 8.4M fp16 (16 MB)
  float* P  = ws;                                           // 8,388,608 f (32 MB)
  unsigned short* ctxh = (unsigned short*)ws;               // 8.4M fp16
  unsigned short* Qh = (unsigned short*)(ws + 8388608);     // 8.4M fp16 [b][h][d][t]
  unsigned short* Kh = (unsigned short*)(ws + 12582912);    // 8.4M fp16 [b][h][d][t]
  unsigned short* Vv = (unsigned short*)(ws + 16777216);    // 8.4M fp16 [b][h][t][d]
  unsigned short* Wqkvh = (unsigned short*)(ws + 20971520); // 786,432 fp16
  unsigned short* Woh   = (unsigned short*)(ws + 21364736); // 262,144 fp16
  float* wbuf = ws + 21495808;                              // 512
  int*   dbuf = (int*)(ws + 21496320);                      // 512
  float* S    = ws + 21496832;                              // 262,144 f (1 MB)

  split_all<<<9216, 256, 0, stream>>>(x, Wq, Wk, Wv, Wo, xh, Wqkvh, Woh);

  qkv_gemm<<<dim3(MTOT / 128, 12), 256, 0, stream>>>(xh, Wqkvh,
                                                     bq, bk, bv, Qh, Kh, Vv);

  fft_fwd_kernel<<<dim3(32, 32), 256, 0, stream>>>(Qh, Kh, P);
  reduce_partials<<<dim3(32, 8), 256, 0, stream>>>(P, S);
  fft_inv_topk_kernel<<<32, 256, 0, stream>>>(S, wbuf, dbuf);
  gather_kernel<<<dim3(32, L_ / 16), 256, 0, stream>>>(Vv, wbuf, dbuf, ctxh);

  o_gemm<<<dim3(MTOT / 128, DM_ / 128), 256, 0, stream>>>(ctxh, Woh, bo, out);
}